// Round 6
// baseline (341.283 us; speedup 1.0000x reference)
//
#include <hip/hip_runtime.h>
#include <hip/hip_bf16.h>
#include <hip/hip_fp16.h>

// Problem constants: B=2, N=10000, M=320000, QD=KD=HD=256, NUM_HEADS=8, dh=32.
#define DHID 256
#define NHEAD 8
#define BATCH 2
#define BSHIFT 5                 // bucket = 32 src rows = 16 KB of Q
#define MAXNB 1024

typedef _Float16 h8 __attribute__((ext_vector_type(8)));
typedef float f4 __attribute__((ext_vector_type(4)));

// ---------------- P0: W transpose->fp16 (z=0,1) + zero seg/hist (z=2) -----
__global__ __launch_bounds__(256) void prep_kernel(
    const float* __restrict__ Wq, const float* __restrict__ Wk,
    _Float16* __restrict__ Wtq, _Float16* __restrict__ Wtk,
    float* __restrict__ seg, int* __restrict__ hist, int segN, int NB)
{
    if (blockIdx.z == 2) {
        int idx = (blockIdx.x * 8 + blockIdx.y) * 256 + threadIdx.y * 32 + threadIdx.x;
        for (int i = idx; i < segN; i += 64 * 256) seg[i] = 0.f;
        if (idx < NB) hist[idx] = 0;
        return;
    }
    const float* W = blockIdx.z ? Wk : Wq;
    _Float16* Wt   = blockIdx.z ? Wtk : Wtq;
    __shared__ float tile[32][33];
    const int tx = threadIdx.x;   // 0..31
    const int ty = threadIdx.y;   // 0..7
    const int n0 = blockIdx.x * 32;
    const int k0 = blockIdx.y * 32;
#pragma unroll
    for (int j = 0; j < 32; j += 8)
        tile[ty + j][tx] = W[(size_t)(k0 + ty + j) * DHID + n0 + tx];
    __syncthreads();
#pragma unroll
    for (int j = 0; j < 32; j += 8)
        Wt[(size_t)(n0 + ty + j) * DHID + k0 + tx] = (_Float16)tile[tx][ty + j];
}

// ---------------- P1: histogram of src buckets ----------------------------
__global__ __launch_bounds__(256) void hist_kernel(
    const int* __restrict__ mask, int* __restrict__ hist, int M, int NB)
{
    __shared__ int lh[MAXNB];
    for (int i = threadIdx.x; i < NB; i += 256) lh[i] = 0;
    __syncthreads();
    for (long e = (long)blockIdx.x * 256 + threadIdx.x; e < M; e += (long)gridDim.x * 256)
        atomicAdd(&lh[mask[e] >> BSHIFT], 1);
    __syncthreads();
    for (int i = threadIdx.x; i < NB; i += 256)
        if (lh[i]) atomicAdd(&hist[i], lh[i]);
}

// ---------------- P2: exclusive scan -> cursor (one wave) -----------------
__global__ void scan_kernel(const int* __restrict__ hist,
                            int* __restrict__ cursor, int NB)
{
    const int lane = threadIdx.x;         // 64 threads
    const int per = (NB + 63) / 64;       // bins per lane (<=16)
    int h[16];
    int s = 0;
    for (int j = 0; j < per; ++j) {
        int i = lane * per + j;
        h[j] = (i < NB) ? hist[i] : 0;
        s += h[j];
    }
    int inc = s;
    for (int d = 1; d < 64; d <<= 1) {
        int t = __shfl_up(inc, d);
        if (lane >= d) inc += t;
    }
    int exc = inc - s;
    for (int j = 0; j < per; ++j) {
        int i = lane * per + j;
        if (i < NB) cursor[i] = exc;
        exc += h[j];
    }
}

// ---------------- P3: scatter edge ids into sorted order ------------------
__global__ __launch_bounds__(256) void scatter_kernel(
    const int* __restrict__ mask, int* __restrict__ cursor,
    int* __restrict__ perm, int M)
{
    for (long e = (long)blockIdx.x * 256 + threadIdx.x; e < M; e += (long)gridDim.x * 256) {
        int bkt = mask[e] >> BSHIFT;
        int pos = atomicAdd(&cursor[bkt], 1);
        perm[pos] = (int)e;
    }
}

// ---------------- MFMA GEMM, A-stationary (unchanged) ---------------------
__global__ __launch_bounds__(256, 2) void gemm_mfma(
    const float* __restrict__ Xq, const float* __restrict__ Xk,
    const _Float16* __restrict__ Wtq, const _Float16* __restrict__ Wtk,
    _Float16* __restrict__ Qh, _Float16* __restrict__ Kh, int Mrows)
{
    const float* X       = blockIdx.z ? Xk : Xq;
    const _Float16* Wt   = blockIdx.z ? Wtk : Wtq;
    _Float16* C          = blockIdx.z ? Kh : Qh;

    __shared__ _Float16 As[64 * 256];
    __shared__ _Float16 Bs[64 * 256];

    const int t    = threadIdx.x;
    const int lane = t & 63;
    const int wave = t >> 6;
    const int rowBase = blockIdx.x * 64;

#pragma unroll
    for (int i = 0; i < 8; ++i) {
        int idx = t + i * 256;
        int row = idx >> 5;
        int c   = idx & 31;
        int grow = rowBase + row;
        f4 v0 = {0,0,0,0}, v1 = {0,0,0,0};
        if (grow < Mrows) {
            const float* p = X + (size_t)grow * DHID + c * 8;
            v0 = *(const f4*)p;
            v1 = *(const f4*)(p + 4);
        }
        h8 hv;
        hv[0]=(_Float16)v0[0]; hv[1]=(_Float16)v0[1]; hv[2]=(_Float16)v0[2]; hv[3]=(_Float16)v0[3];
        hv[4]=(_Float16)v1[0]; hv[5]=(_Float16)v1[1]; hv[6]=(_Float16)v1[2]; hv[7]=(_Float16)v1[3];
        int sc = c ^ (row & 7);
        *(h8*)&As[row * 256 + sc * 8] = hv;
    }

    const int ar   = wave * 16 + (lane & 15);
    const int quad = lane >> 4;

    for (int ct64 = 0; ct64 < 4; ++ct64) {
#pragma unroll
        for (int i = 0; i < 8; ++i) {
            int idx = t + i * 256;
            int n = idx >> 5;
            int c = idx & 31;
            h8 hv = *(const h8*)(Wt + (size_t)(ct64 * 64 + n) * DHID + c * 8);
            int sc = c ^ (n & 7);
            *(h8*)&Bs[n * 256 + sc * 8] = hv;
        }
        __syncthreads();

        f4 acc[4] = {{0,0,0,0},{0,0,0,0},{0,0,0,0},{0,0,0,0}};
#pragma unroll
        for (int kc = 0; kc < 8; ++kc) {
            int ac = (kc * 4 + quad) ^ (ar & 7);
            h8 afrag = *(const h8*)&As[ar * 256 + ac * 8];
#pragma unroll
            for (int ct = 0; ct < 4; ++ct) {
                int bn = ct * 16 + (lane & 15);
                int bc = (kc * 4 + quad) ^ (bn & 7);
                h8 bfrag = *(const h8*)&Bs[bn * 256 + bc * 8];
                acc[ct] = __builtin_amdgcn_mfma_f32_16x16x32_f16(afrag, bfrag, acc[ct], 0, 0, 0);
            }
        }

#pragma unroll
        for (int ct = 0; ct < 4; ++ct) {
#pragma unroll
            for (int r = 0; r < 4; ++r) {
                int grow = rowBase + wave * 16 + quad * 4 + r;
                if (grow < Mrows)
                    C[(size_t)grow * DHID + ct64 * 64 + ct * 16 + (lane & 15)] = (_Float16)acc[ct][r];
            }
        }
        __syncthreads();
    }
}

// ---------------- Edge kernel: sorted order, 512 edges per block ----------
// Block processes sorted positions [bx*512, bx*512+512): Q-gathers land in
// a <=32KB window (L1-resident, ~16x reuse); K stays random. Lane 8g+h owns
// head h of group-edge g; per-wave loop over 16 groups with index prefetch.
__global__ __launch_bounds__(256) void edge_kernel(
    const _Float16* __restrict__ Qh, const _Float16* __restrict__ Kh,
    const int* __restrict__ mask, const int* __restrict__ perm,
    float* __restrict__ out, float* __restrict__ seg, int M, int N)
{
    const int lane = threadIdx.x & 63;
    const int wave = threadIdx.x >> 6;
    const int g = lane >> 3;        // group-edge 0..7
    const int h = lane & 7;         // head 0..7
    const int b = blockIdx.y;
    const long base = (long)blockIdx.x * 512;

    const _Float16* Qb = Qh + (size_t)b * N * DHID;
    const _Float16* Kb = Kh + (size_t)b * N * DHID;

    // preload indices for this wave's first group
    int pv = 0, sv = 0, dv = 0;
    if (lane < 8) {
        long le = base + (long)wave * 8 + lane;
        int p = (le < M) ? perm[le] : 0;
        pv = p; sv = mask[p]; dv = mask[M + p];
    }

    for (int gi = wave; gi < 64; gi += 4) {
        const long e0 = base + (long)gi * 8;
        const int pe  = __shfl(pv, g);
        const int src = __shfl(sv, g);
        const int dst = __shfl(dv, g);

        const h8* qp = (const h8*)(Qb + (size_t)src * DHID + h * 32);
        const h8* kp = (const h8*)(Kb + (size_t)dst * DHID + h * 32);
        h8 a0 = qp[0], a1 = qp[1], a2 = qp[2], a3 = qp[3];
        h8 c0 = kp[0], c1 = kp[1], c2 = kp[2], c3 = kp[3];

        // prefetch next group's indices while gathers are in flight
        if (gi + 4 < 64 && lane < 8) {
            long le = base + (long)(gi + 4) * 8 + lane;
            int p = (le < M) ? perm[le] : 0;
            pv = p; sv = mask[p]; dv = mask[M + p];
        }

        float s0 = 0.f, s1 = 0.f, s2 = 0.f, s3 = 0.f;
#pragma unroll
        for (int u = 0; u < 8; ++u) {
            s0 += (float)a0[u] * (float)c0[u];
            s1 += (float)a1[u] * (float)c1[u];
            s2 += (float)a2[u] * (float)c2[u];
            s3 += (float)a3[u] * (float)c3[u];
        }
        float s = (s0 + s1) + (s2 + s3);

        if (e0 + g < M) {
            float ev = expf(s * 0.0625f);   // 1/sqrt(256) = 1/16
            out[((size_t)b * M + pe) * NHEAD + h] = ev;
            atomicAdd(seg + ((size_t)b * N + src) * NHEAD + h, ev);
        }
    }
}

// ---------------- Normalize: out = e / (seg[src] + 1e-16) -----------------
__global__ __launch_bounds__(256) void norm_kernel(
    const int* __restrict__ mask, const float* __restrict__ seg,
    float* __restrict__ out, int M, int N, int BM)
{
    int idx = blockIdx.x * 256 + threadIdx.x;   // idx = b*M + e
    if (idx >= BM) return;
    int b = idx / M;
    int e = idx - b * M;
    int src = mask[e];
    const float4* s4 = (const float4*)(seg + ((size_t)b * N + src) * NHEAD);
    float4 s0 = s4[0], s1 = s4[1];
    float4* o4 = (float4*)(out + (size_t)idx * NHEAD);
    float4 o0 = o4[0], o1 = o4[1];
    o0.x /= (s0.x + 1e-16f); o0.y /= (s0.y + 1e-16f);
    o0.z /= (s0.z + 1e-16f); o0.w /= (s0.w + 1e-16f);
    o1.x /= (s1.x + 1e-16f); o1.y /= (s1.y + 1e-16f);
    o1.z /= (s1.z + 1e-16f); o1.w /= (s1.w + 1e-16f);
    o4[0] = o0; o4[1] = o1;
}

extern "C" void kernel_launch(void* const* d_in, const int* in_sizes, int n_in,
                              void* d_out, int out_size, void* d_ws, size_t ws_size,
                              hipStream_t stream) {
    const float* x_q  = (const float*)d_in[0];
    const float* x_k  = (const float*)d_in[1];
    const int*   mask = (const int*)d_in[2];
    const float* w_q  = (const float*)d_in[3];
    const float* w_k  = (const float*)d_in[4];
    float* out = (float*)d_out;

    const int M = in_sizes[2] / 2;                 // 320000
    const int N = in_sizes[0] / (BATCH * DHID);    // 10000
    const int Mrows = BATCH * N;                   // 20000
    const int NB = (N + (1 << BSHIFT) - 1) >> BSHIFT;   // 313

    _Float16* Qh   = (_Float16*)d_ws;
    _Float16* Kh   = Qh  + (size_t)Mrows * DHID;
    _Float16* Wtq  = Kh  + (size_t)Mrows * DHID;
    _Float16* Wtk  = Wtq + (size_t)DHID * DHID;
    float*    seg  = (float*)(Wtk + (size_t)DHID * DHID);
    int*      hist = (int*)(seg + (size_t)BATCH * N * NHEAD);
    int*      curs = hist + MAXNB;
    int*      perm = curs + MAXNB;

    // P0: transpose W + zero seg/hist
    prep_kernel<<<dim3(DHID / 32, DHID / 32, 3), dim3(32, 8), 0, stream>>>(
        w_q, w_k, Wtq, Wtk, seg, hist, BATCH * N * NHEAD, NB);

    // P1..P3: bucket-sort edges by src>>5
    hist_kernel<<<128, 256, 0, stream>>>(mask, hist, M, NB);
    scan_kernel<<<1, 64, 0, stream>>>(hist, curs, NB);
    scatter_kernel<<<256, 256, 0, stream>>>(mask, curs, perm, M);

    // GEMM
    dim3 ggrid((Mrows + 63) / 64, 1, 2);
    gemm_mfma<<<ggrid, 256, 0, stream>>>(x_q, x_k, Wtq, Wtk, Qh, Kh, Mrows);

    // edge: 512 sorted edges per block
    dim3 egrid((unsigned)((M + 511) / 512), BATCH);
    edge_kernel<<<egrid, 256, 0, stream>>>(Qh, Kh, mask, perm, out, seg, M, N);

    const int BM = BATCH * M;
    norm_kernel<<<(BM + 255) / 256, 256, 0, stream>>>(mask, seg, out, M, N, BM);
}

// Round 7
// 211.358 us; speedup vs baseline: 1.6147x; 1.6147x over previous
//
#include <hip/hip_runtime.h>
#include <hip/hip_bf16.h>
#include <hip/hip_fp16.h>

// Problem constants: B=2, N=10000, M=320000, QD=KD=HD=256, NUM_HEADS=8, dh=32.
#define DHID 256
#define NHEAD 8
#define BATCH 2

typedef _Float16 h8 __attribute__((ext_vector_type(8)));
typedef float f4 __attribute__((ext_vector_type(4)));

// ---------------- P0: W transpose->fp16 (z=0,1) + zero seg (z=2) ----------
__global__ __launch_bounds__(256) void prep_kernel(
    const float* __restrict__ Wq, const float* __restrict__ Wk,
    _Float16* __restrict__ Wtq, _Float16* __restrict__ Wtk,
    float* __restrict__ seg, int segN)
{
    if (blockIdx.z == 2) {
        int idx = (blockIdx.x * 8 + blockIdx.y) * 256 + threadIdx.y * 32 + threadIdx.x;
        for (int i = idx; i < segN; i += 64 * 256) seg[i] = 0.f;
        return;
    }
    const float* W = blockIdx.z ? Wk : Wq;
    _Float16* Wt   = blockIdx.z ? Wtk : Wtq;
    __shared__ float tile[32][33];
    const int tx = threadIdx.x;   // 0..31
    const int ty = threadIdx.y;   // 0..7
    const int n0 = blockIdx.x * 32;
    const int k0 = blockIdx.y * 32;
#pragma unroll
    for (int j = 0; j < 32; j += 8)
        tile[ty + j][tx] = W[(size_t)(k0 + ty + j) * DHID + n0 + tx];
    __syncthreads();
#pragma unroll
    for (int j = 0; j < 32; j += 8)
        Wt[(size_t)(n0 + ty + j) * DHID + k0 + tx] = (_Float16)tile[tx][ty + j];
}

// ---------------- MFMA GEMM: A-tile in 32 KB LDS, B direct from L2 --------
// W^T is 128 KB and shared by all blocks -> L2-hot; skipping B staging
// removes 4x32KB LDS + 8 barriers. One barrier per block total.
// 5 blocks/CU by LDS (was 2 with 64 KB).
__global__ __launch_bounds__(256) void gemm_mfma(
    const float* __restrict__ Xq, const float* __restrict__ Xk,
    const _Float16* __restrict__ Wtq, const _Float16* __restrict__ Wtk,
    _Float16* __restrict__ Qh, _Float16* __restrict__ Kh, int Mrows)
{
    const float* X     = blockIdx.z ? Xk : Xq;
    const _Float16* Wt = blockIdx.z ? Wtk : Wtq;
    _Float16* C        = blockIdx.z ? Kh : Qh;

    __shared__ _Float16 As[64 * 256];   // 32 KB, [row][k] swizzled

    const int t    = threadIdx.x;
    const int lane = t & 63;
    const int wave = t >> 6;
    const int rowBase = blockIdx.x * 64;

    // stage A: 64 rows x 256 k, fp32 -> fp16. chunk = 8 halves = 16B, 32/row.
#pragma unroll
    for (int i = 0; i < 8; ++i) {
        int idx = t + i * 256;          // 0..2047
        int row = idx >> 5;
        int c   = idx & 31;
        int grow = rowBase + row;
        f4 v0 = {0,0,0,0}, v1 = {0,0,0,0};
        if (grow < Mrows) {
            const float* p = X + (size_t)grow * DHID + c * 8;
            v0 = *(const f4*)p;
            v1 = *(const f4*)(p + 4);
        }
        h8 hv;
        hv[0]=(_Float16)v0[0]; hv[1]=(_Float16)v0[1]; hv[2]=(_Float16)v0[2]; hv[3]=(_Float16)v0[3];
        hv[4]=(_Float16)v1[0]; hv[5]=(_Float16)v1[1]; hv[6]=(_Float16)v1[2]; hv[7]=(_Float16)v1[3];
        int sc = c ^ (row & 7);
        *(h8*)&As[row * 256 + sc * 8] = hv;
    }
    __syncthreads();

    const int m    = lane & 15;
    const int quad = lane >> 4;
    const int ar   = wave * 16 + m;

    // preload all 8 A-frags (rows fixed, k = kc*32 + quad*8)
    h8 af[8];
#pragma unroll
    for (int kc = 0; kc < 8; ++kc) {
        int ac = (kc * 4 + quad) ^ (ar & 7);
        af[kc] = *(const h8*)&As[ar * 256 + ac * 8];
    }

    // B frag for col-tile ct: B[n = ct*16+m][k = kc*32 + quad*8], from global.
    const _Float16* wbase = Wt + (size_t)m * DHID + quad * 8;
#pragma unroll
    for (int ct = 0; ct < 16; ++ct) {
        const _Float16* wp = wbase + (size_t)ct * 16 * DHID;
        h8 bf[8];
#pragma unroll
        for (int kc = 0; kc < 8; ++kc)
            bf[kc] = *(const h8*)(wp + kc * 32);
        f4 acc = {0, 0, 0, 0};
#pragma unroll
        for (int kc = 0; kc < 8; ++kc)
            acc = __builtin_amdgcn_mfma_f32_16x16x32_f16(af[kc], bf[kc], acc, 0, 0, 0);
        // D[row=quad*4+r][col=m]
        int col = ct * 16 + m;
#pragma unroll
        for (int r = 0; r < 4; ++r) {
            int grow = rowBase + wave * 16 + quad * 4 + r;
            if (grow < Mrows)
                C[(size_t)grow * DHID + col] = (_Float16)acc[r];
        }
    }
}

// ---------------- Edge kernel: 8 edges/wave (round-5 winner) --------------
// lane 8g+h owns head h (32 contiguous channels) of edge g; explicit load
// phase; exp/store/atomic on all 64 lanes.
// Global max subtraction cancels in e/seg -> skipped.
__global__ __launch_bounds__(256) void edge_kernel(
    const _Float16* __restrict__ Qh, const _Float16* __restrict__ Kh,
    const int* __restrict__ mask, float* __restrict__ out,
    float* __restrict__ seg, int M, int N)
{
    const int lane = threadIdx.x & 63;
    const int wave = threadIdx.x >> 6;
    const int g = lane >> 3;        // edge-in-wave 0..7
    const int h = lane & 7;         // head 0..7
    const long e0 = ((long)blockIdx.x * 4 + wave) * 8;
    const int b = blockIdx.y;
    if (e0 >= M) return;

    // lanes 0..7 load the 8 src indices, lanes 8..15 the 8 dst indices
    int idxv = 0;
    {
        long le = e0 + (lane & 7);
        if (le >= M) le = M - 1;
        if (lane < 8)       idxv = mask[le];
        else if (lane < 16) idxv = mask[M + le];
    }
    const int src = __shfl(idxv, g);
    const int dst = __shfl(idxv, 8 + g);

    const h8* qp = (const h8*)(Qh + ((size_t)b * N + src) * DHID + h * 32);
    const h8* kp = (const h8*)(Kh + ((size_t)b * N + dst) * DHID + h * 32);

    // ---- load phase: 8 independent 16B gathers ----
    h8 a0 = qp[0], a1 = qp[1], a2 = qp[2], a3 = qp[3];
    h8 c0 = kp[0], c1 = kp[1], c2 = kp[2], c3 = kp[3];

    // ---- compute phase ----
    float s0 = 0.f, s1 = 0.f, s2 = 0.f, s3 = 0.f;
#pragma unroll
    for (int u = 0; u < 8; ++u) {
        s0 += (float)a0[u] * (float)c0[u];
        s1 += (float)a1[u] * (float)c1[u];
        s2 += (float)a2[u] * (float)c2[u];
        s3 += (float)a3[u] * (float)c3[u];
    }
    float s = (s0 + s1) + (s2 + s3);

    const long e = e0 + g;
    if (e < M) {
        float ev = expf(s * 0.0625f);   // 1/sqrt(256) = 1/16
        out[((size_t)b * M + e) * NHEAD + h] = ev;   // 256B contiguous per wave
        atomicAdd(seg + ((size_t)b * N + src) * NHEAD + h, ev);
    }
}

// ---------------- Normalize: out = e / (seg[src] + 1e-16) -----------------
__global__ __launch_bounds__(256) void norm_kernel(
    const int* __restrict__ mask, const float* __restrict__ seg,
    float* __restrict__ out, int M, int N, int BM)
{
    int idx = blockIdx.x * 256 + threadIdx.x;   // idx = b*M + e
    if (idx >= BM) return;
    int b = idx / M;
    int e = idx - b * M;
    int src = mask[e];
    const float4* s4 = (const float4*)(seg + ((size_t)b * N + src) * NHEAD);
    float4 s0 = s4[0], s1 = s4[1];
    float4* o4 = (float4*)(out + (size_t)idx * NHEAD);
    float4 o0 = o4[0], o1 = o4[1];
    o0.x /= (s0.x + 1e-16f); o0.y /= (s0.y + 1e-16f);
    o0.z /= (s0.z + 1e-16f); o0.w /= (s0.w + 1e-16f);
    o1.x /= (s1.x + 1e-16f); o1.y /= (s1.y + 1e-16f);
    o1.z /= (s1.z + 1e-16f); o1.w /= (s1.w + 1e-16f);
    o4[0] = o0; o4[1] = o1;
}

extern "C" void kernel_launch(void* const* d_in, const int* in_sizes, int n_in,
                              void* d_out, int out_size, void* d_ws, size_t ws_size,
                              hipStream_t stream) {
    const float* x_q  = (const float*)d_in[0];
    const float* x_k  = (const float*)d_in[1];
    const int*   mask = (const int*)d_in[2];
    const float* w_q  = (const float*)d_in[3];
    const float* w_k  = (const float*)d_in[4];
    float* out = (float*)d_out;

    const int M = in_sizes[2] / 2;                 // 320000
    const int N = in_sizes[0] / (BATCH * DHID);    // 10000
    const int Mrows = BATCH * N;                   // 20000

    _Float16* Qh  = (_Float16*)d_ws;
    _Float16* Kh  = Qh  + (size_t)Mrows * DHID;
    _Float16* Wtq = Kh  + (size_t)Mrows * DHID;
    _Float16* Wtk = Wtq + (size_t)DHID * DHID;
    float*    seg = (float*)(Wtk + (size_t)DHID * DHID);

    // P0: transpose W to fp16 + zero seg (one launch)
    prep_kernel<<<dim3(DHID / 32, DHID / 32, 3), dim3(32, 8), 0, stream>>>(
        w_q, w_k, Wtq, Wtk, seg, BATCH * N * NHEAD);

    dim3 ggrid((Mrows + 63) / 64, 1, 2);
    gemm_mfma<<<ggrid, 256, 0, stream>>>(x_q, x_k, Wtq, Wtk, Qh, Kh, Mrows);

    // 8 edges per wave, 4 waves per block
    long waves = (M + 7) / 8;
    dim3 egrid((unsigned)((waves + 3) / 4), BATCH);
    edge_kernel<<<egrid, 256, 0, stream>>>(Qh, Kh, mask, out, seg, M, N);

    const int BM = BATCH * M;
    norm_kernel<<<(BM + 255) / 256, 256, 0, stream>>>(mask, seg, out, M, N, BM);
}

// Round 8
// 181.791 us; speedup vs baseline: 1.8773x; 1.1626x over previous
//
#include <hip/hip_runtime.h>
#include <hip/hip_bf16.h>
#include <hip/hip_fp16.h>

// Problem constants: B=2, N=10000, M=320000, QD=KD=HD=256, NUM_HEADS=8, dh=32.
#define DHID 256
#define NHEAD 8
#define BATCH 2

typedef _Float16 h8 __attribute__((ext_vector_type(8)));
typedef float f4 __attribute__((ext_vector_type(4)));

// ---------------- P0: W transpose->fp16 (z=0,1) + zero seg (z=2) ----------
__global__ __launch_bounds__(256) void prep_kernel(
    const float* __restrict__ Wq, const float* __restrict__ Wk,
    _Float16* __restrict__ Wtq, _Float16* __restrict__ Wtk,
    float* __restrict__ seg, int segN)
{
    if (blockIdx.z == 2) {
        int idx = (blockIdx.x * 8 + blockIdx.y) * 256 + threadIdx.y * 32 + threadIdx.x;
        for (int i = idx; i < segN; i += 64 * 256) seg[i] = 0.f;
        return;
    }
    const float* W = blockIdx.z ? Wk : Wq;
    _Float16* Wt   = blockIdx.z ? Wtk : Wtq;
    __shared__ float tile[32][33];
    const int tx = threadIdx.x;   // 0..31
    const int ty = threadIdx.y;   // 0..7
    const int n0 = blockIdx.x * 32;
    const int k0 = blockIdx.y * 32;
#pragma unroll
    for (int j = 0; j < 32; j += 8)
        tile[ty + j][tx] = W[(size_t)(k0 + ty + j) * DHID + n0 + tx];
    __syncthreads();
#pragma unroll
    for (int j = 0; j < 32; j += 8)
        Wt[(size_t)(n0 + ty + j) * DHID + k0 + tx] = (_Float16)tile[tx][ty + j];
}

// ---------------- MFMA GEMM, A-stationary (round-5 winner, reverted) ------
__global__ __launch_bounds__(256, 2) void gemm_mfma(
    const float* __restrict__ Xq, const float* __restrict__ Xk,
    const _Float16* __restrict__ Wtq, const _Float16* __restrict__ Wtk,
    _Float16* __restrict__ Qh, _Float16* __restrict__ Kh, int Mrows)
{
    const float* X       = blockIdx.z ? Xk : Xq;
    const _Float16* Wt   = blockIdx.z ? Wtk : Wtq;
    _Float16* C          = blockIdx.z ? Kh : Qh;

    __shared__ _Float16 As[64 * 256];   // 32 KB, [row][k] swizzled
    __shared__ _Float16 Bs[64 * 256];   // 32 KB, [n][k]   swizzled

    const int t    = threadIdx.x;
    const int lane = t & 63;
    const int wave = t >> 6;
    const int rowBase = blockIdx.x * 64;

#pragma unroll
    for (int i = 0; i < 8; ++i) {
        int idx = t + i * 256;          // 0..2047
        int row = idx >> 5;
        int c   = idx & 31;
        int grow = rowBase + row;
        f4 v0 = {0,0,0,0}, v1 = {0,0,0,0};
        if (grow < Mrows) {
            const float* p = X + (size_t)grow * DHID + c * 8;
            v0 = *(const f4*)p;
            v1 = *(const f4*)(p + 4);
        }
        h8 hv;
        hv[0]=(_Float16)v0[0]; hv[1]=(_Float16)v0[1]; hv[2]=(_Float16)v0[2]; hv[3]=(_Float16)v0[3];
        hv[4]=(_Float16)v1[0]; hv[5]=(_Float16)v1[1]; hv[6]=(_Float16)v1[2]; hv[7]=(_Float16)v1[3];
        int sc = c ^ (row & 7);
        *(h8*)&As[row * 256 + sc * 8] = hv;
    }

    const int ar   = wave * 16 + (lane & 15);
    const int quad = lane >> 4;

    for (int ct64 = 0; ct64 < 4; ++ct64) {
#pragma unroll
        for (int i = 0; i < 8; ++i) {
            int idx = t + i * 256;
            int n = idx >> 5;
            int c = idx & 31;
            h8 hv = *(const h8*)(Wt + (size_t)(ct64 * 64 + n) * DHID + c * 8);
            int sc = c ^ (n & 7);
            *(h8*)&Bs[n * 256 + sc * 8] = hv;
        }
        __syncthreads();

        f4 acc[4] = {{0,0,0,0},{0,0,0,0},{0,0,0,0},{0,0,0,0}};
#pragma unroll
        for (int kc = 0; kc < 8; ++kc) {            // K chunk of 32
            int ac = (kc * 4 + quad) ^ (ar & 7);
            h8 afrag = *(const h8*)&As[ar * 256 + ac * 8];
#pragma unroll
            for (int ct = 0; ct < 4; ++ct) {
                int bn = ct * 16 + (lane & 15);
                int bc = (kc * 4 + quad) ^ (bn & 7);
                h8 bfrag = *(const h8*)&Bs[bn * 256 + bc * 8];
                acc[ct] = __builtin_amdgcn_mfma_f32_16x16x32_f16(afrag, bfrag, acc[ct], 0, 0, 0);
            }
        }

#pragma unroll
        for (int ct = 0; ct < 4; ++ct) {
#pragma unroll
            for (int r = 0; r < 4; ++r) {
                int grow = rowBase + wave * 16 + quad * 4 + r;
                if (grow < Mrows)
                    C[(size_t)grow * DHID + ct64 * 64 + ct * 16 + (lane & 15)] = (_Float16)acc[ct][r];
            }
        }
        __syncthreads();
    }
}

// ---------------- Edge kernel: 8 edges/wave + XCD-batch affinity ----------
// 1D grid; bid%8 in {0..3} -> batch 0, {4..7} -> batch 1. Consecutive block
// IDs round-robin XCDs, so each XCD sees (mostly) ONE batch's Q+K working
// set (10.2 MB vs 20.5) in its 4 MB L2 -> higher hit rate, lower fetch.
// Lane 8g+h owns head h of edge g; explicit 8-gather load phase.
// Global max subtraction cancels in e/seg -> skipped.
__global__ __launch_bounds__(256) void edge_kernel(
    const _Float16* __restrict__ Qh, const _Float16* __restrict__ Kh,
    const int* __restrict__ mask, float* __restrict__ out,
    float* __restrict__ seg, int M, int N)
{
    const int lane = threadIdx.x & 63;
    const int wave = threadIdx.x >> 6;
    const int g = lane >> 3;        // edge-in-wave 0..7
    const int h = lane & 7;         // head 0..7

    // bid -> (xblk, b):  r = bid%8;  b = r<4 ? 0 : 1;  xblk = (bid/8)*4 + (r&3)
    const int bid  = blockIdx.x;
    const int r8   = bid & 7;
    const int b    = (r8 >= 4);
    const int xblk = (bid >> 3) * 4 + (r8 & 3);

    const long e0 = ((long)xblk * 4 + wave) * 8;
    if (e0 >= M) return;

    int idxv = 0;
    {
        long le = e0 + (lane & 7);
        if (le >= M) le = M - 1;
        if (lane < 8)       idxv = mask[le];
        else if (lane < 16) idxv = mask[M + le];
    }
    const int src = __shfl(idxv, g);
    const int dst = __shfl(idxv, 8 + g);

    const h8* qp = (const h8*)(Qh + ((size_t)b * N + src) * DHID + h * 32);
    const h8* kp = (const h8*)(Kh + ((size_t)b * N + dst) * DHID + h * 32);

    // ---- load phase: 8 independent 16B gathers ----
    h8 a0 = qp[0], a1 = qp[1], a2 = qp[2], a3 = qp[3];
    h8 c0 = kp[0], c1 = kp[1], c2 = kp[2], c3 = kp[3];

    // ---- compute phase ----
    float s0 = 0.f, s1 = 0.f, s2 = 0.f, s3 = 0.f;
#pragma unroll
    for (int u = 0; u < 8; ++u) {
        s0 += (float)a0[u] * (float)c0[u];
        s1 += (float)a1[u] * (float)c1[u];
        s2 += (float)a2[u] * (float)c2[u];
        s3 += (float)a3[u] * (float)c3[u];
    }
    float s = (s0 + s1) + (s2 + s3);

    const long e = e0 + g;
    if (e < M) {
        float ev = expf(s * 0.0625f);   // 1/sqrt(256) = 1/16
        out[((size_t)b * M + e) * NHEAD + h] = ev;   // 256B contiguous per wave
        atomicAdd(seg + ((size_t)b * N + src) * NHEAD + h, ev);
    }
}

// ---------------- Normalize: out = e / (seg[src] + 1e-16) -----------------
__global__ __launch_bounds__(256) void norm_kernel(
    const int* __restrict__ mask, const float* __restrict__ seg,
    float* __restrict__ out, int M, int N, int BM)
{
    int idx = blockIdx.x * 256 + threadIdx.x;   // idx = b*M + e
    if (idx >= BM) return;
    int b = idx / M;
    int e = idx - b * M;
    int src = mask[e];
    const float4* s4 = (const float4*)(seg + ((size_t)b * N + src) * NHEAD);
    float4 s0 = s4[0], s1 = s4[1];
    float4* o4 = (float4*)(out + (size_t)idx * NHEAD);
    float4 o0 = o4[0], o1 = o4[1];
    o0.x /= (s0.x + 1e-16f); o0.y /= (s0.y + 1e-16f);
    o0.z /= (s0.z + 1e-16f); o0.w /= (s0.w + 1e-16f);
    o1.x /= (s1.x + 1e-16f); o1.y /= (s1.y + 1e-16f);
    o1.z /= (s1.z + 1e-16f); o1.w /= (s1.w + 1e-16f);
    o4[0] = o0; o4[1] = o1;
}

extern "C" void kernel_launch(void* const* d_in, const int* in_sizes, int n_in,
                              void* d_out, int out_size, void* d_ws, size_t ws_size,
                              hipStream_t stream) {
    const float* x_q  = (const float*)d_in[0];
    const float* x_k  = (const float*)d_in[1];
    const int*   mask = (const int*)d_in[2];
    const float* w_q  = (const float*)d_in[3];
    const float* w_k  = (const float*)d_in[4];
    float* out = (float*)d_out;

    const int M = in_sizes[2] / 2;                 // 320000
    const int N = in_sizes[0] / (BATCH * DHID);    // 10000
    const int Mrows = BATCH * N;                   // 20000

    _Float16* Qh  = (_Float16*)d_ws;
    _Float16* Kh  = Qh  + (size_t)Mrows * DHID;
    _Float16* Wtq = Kh  + (size_t)Mrows * DHID;
    _Float16* Wtk = Wtq + (size_t)DHID * DHID;
    float*    seg = (float*)(Wtk + (size_t)DHID * DHID);

    // P0: transpose W to fp16 + zero seg (one launch)
    prep_kernel<<<dim3(DHID / 32, DHID / 32, 3), dim3(32, 8), 0, stream>>>(
        w_q, w_k, Wtq, Wtk, seg, BATCH * N * NHEAD);

    dim3 ggrid((Mrows + 63) / 64, 1, 2);
    gemm_mfma<<<ggrid, 256, 0, stream>>>(x_q, x_k, Wtq, Wtk, Qh, Kh, Mrows);

    // edge: 1D grid, 4 waves x 8 edges per block, batch via bid%8 swizzle
    long xblocks = ((long)(M + 7) / 8 + 3) / 4;      // blocks per batch
    long bidmax  = ((xblocks + 3) / 4) * 8;          // cover both batches
    edge_kernel<<<(unsigned)bidmax, 256, 0, stream>>>(Qh, Kh, mask, out, seg, M, N);

    const int BM = BATCH * M;
    norm_kernel<<<(BM + 255) / 256, 256, 0, stream>>>(mask, seg, out, M, N, BM);
}